// Round 1
// baseline (1339.300 us; speedup 1.0000x reference)
//
#include <hip/hip_runtime.h>
#include <math.h>

// Problem constants (from reference): B=4, S=4096, d_model=256, d_k=d_v=64
#define B_   4
#define S_   4096
#define DM   256
#define DK   64
#define DV   64
#define NROWS (B_ * S_)          // 16384 total (b,s) rows
#define JS_OUT 4                 // grid.y splits of the j (key) dimension
#define NWAVE 4                  // waves per block in attn kernel (inner j-split)
// total j-splits = JS_OUT * NWAVE = 16, each covering S/16 = 256 keys

// ---------------------------------------------------------------------------
// Kernel 1: projection  out[row][col] = relu( sum_m x[row][m] * w[col][m] )
// x: [NROWS][256]  w: [64][256]  out: [NROWS][64]
// blockIdx.y == 0 -> (q, w_q, qp); == 1 -> (k, w_k, kp)
// 256 threads: col = tid&63, row-group = tid>>6, 4 rows per row-group,
// 16 rows per block. w read per-lane (float4, L1/L2 cached), x rows are
// wave-uniform -> scalar loads.
// ---------------------------------------------------------------------------
__global__ __launch_bounds__(256) void proj_kernel(
    const float* __restrict__ q, const float* __restrict__ k,
    const float* __restrict__ w_q, const float* __restrict__ w_k,
    float* __restrict__ qp, float* __restrict__ kp)
{
    const float* x;
    const float* w;
    float* o;
    if (blockIdx.y == 0) { x = q; w = w_q; o = qp; }
    else                 { x = k; w = w_k; o = kp; }

    const int col  = threadIdx.x & 63;
    const int rg   = threadIdx.x >> 6;          // 0..3
    const int row0 = blockIdx.x * 16 + rg * 4;  // 4 consecutive rows

    float acc0 = 0.f, acc1 = 0.f, acc2 = 0.f, acc3 = 0.f;
    const float4* wv4 = (const float4*)(w + (size_t)col * DM);
    const float4* x0  = (const float4*)(x + (size_t)(row0 + 0) * DM);
    const float4* x1  = (const float4*)(x + (size_t)(row0 + 1) * DM);
    const float4* x2  = (const float4*)(x + (size_t)(row0 + 2) * DM);
    const float4* x3  = (const float4*)(x + (size_t)(row0 + 3) * DM);

#pragma unroll 8
    for (int m4 = 0; m4 < DM / 4; ++m4) {
        const float4 wv = wv4[m4];
        float4 a;
        a = x0[m4]; acc0 += a.x * wv.x + a.y * wv.y + a.z * wv.z + a.w * wv.w;
        a = x1[m4]; acc1 += a.x * wv.x + a.y * wv.y + a.z * wv.z + a.w * wv.w;
        a = x2[m4]; acc2 += a.x * wv.x + a.y * wv.y + a.z * wv.z + a.w * wv.w;
        a = x3[m4]; acc3 += a.x * wv.x + a.y * wv.y + a.z * wv.z + a.w * wv.w;
    }
    o[(size_t)(row0 + 0) * DK + col] = fmaxf(acc0, 0.f);
    o[(size_t)(row0 + 1) * DK + col] = fmaxf(acc1, 0.f);
    o[(size_t)(row0 + 2) * DK + col] = fmaxf(acc2, 0.f);
    o[(size_t)(row0 + 3) * DK + col] = fmaxf(acc3, 0.f);
}

// ---------------------------------------------------------------------------
// Kernel 2: attention partials.
// Scores are tiny (|s| <= ~5) so softmax needs no max-subtraction:
//   num[row][d] = sum_{j != 0} exp(s_j / 8) * v[j][d],  den[row] = sum exp(s_j/8)
// (reference sets attn[:,:,0] = -1e38 -> p_0 == 0 exactly, so skip j==0.)
//
// Block: 256 threads = 4 waves. lane (0..63) = q-row within a 64-row group,
// wave = inner j-split. grid = (NROWS/64, JS_OUT). Each thread keeps its
// qp row (64 f32) and num accumulator (64 f32) in VGPRs. kp/v rows are
// wave-uniform global reads. After the j-loop, tree-reduce the 4 waves
// through LDS and write one partial per blockIdx.y.
// ---------------------------------------------------------------------------
__global__ __launch_bounds__(256) void attn_partial(
    const float* __restrict__ qp, const float* __restrict__ kp,
    const float* __restrict__ v, float* __restrict__ num_part,
    float* __restrict__ den_part)
{
    __shared__ float shn[2][64][65];   // +1 pad: conflict-free lane-major access
    __shared__ float shd[2][64];

    const int lane = threadIdx.x & 63;
    const int w    = threadIdx.x >> 6;              // 0..3
    const int grow = blockIdx.x * 64 + lane;        // global (b,s) row
    const int b    = blockIdx.x >> 6;               // 64 row-groups per batch (uniform!)
    const int j0   = (blockIdx.y * NWAVE + w) * (S_ / (JS_OUT * NWAVE));

    float4 qv[16], nv[16];
    const float4* qrow = (const float4*)(qp + (size_t)grow * DK);
#pragma unroll
    for (int i = 0; i < 16; ++i) {
        qv[i] = qrow[i];
        nv[i] = make_float4(0.f, 0.f, 0.f, 0.f);
    }
    float den = 0.f;

    const float* kbase = kp + (size_t)b * S_ * DK;
    const float* vbase = v  + (size_t)b * S_ * DV;

    for (int jj = 0; jj < S_ / (JS_OUT * NWAVE); ++jj) {
        const int j = j0 + jj;
        if (j == 0) continue;   // masked column: p_0 == 0
        const float4* krow = (const float4*)(kbase + (size_t)j * DK);
        const float4* vrow = (const float4*)(vbase + (size_t)j * DV);

        float s0 = 0.f, s1 = 0.f, s2 = 0.f, s3 = 0.f;
#pragma unroll
        for (int i = 0; i < 16; i += 4) {
            float4 a = krow[i + 0];
            s0 += qv[i + 0].x * a.x + qv[i + 0].y * a.y + qv[i + 0].z * a.z + qv[i + 0].w * a.w;
            a = krow[i + 1];
            s1 += qv[i + 1].x * a.x + qv[i + 1].y * a.y + qv[i + 1].z * a.z + qv[i + 1].w * a.w;
            a = krow[i + 2];
            s2 += qv[i + 2].x * a.x + qv[i + 2].y * a.y + qv[i + 2].z * a.z + qv[i + 2].w * a.w;
            a = krow[i + 3];
            s3 += qv[i + 3].x * a.x + qv[i + 3].y * a.y + qv[i + 3].z * a.z + qv[i + 3].w * a.w;
        }
        const float e = __expf(((s0 + s1) + (s2 + s3)) * 0.125f);  // / sqrt(64)
        den += e;
#pragma unroll
        for (int i = 0; i < 16; ++i) {
            const float4 vv = vrow[i];
            nv[i].x += e * vv.x;
            nv[i].y += e * vv.y;
            nv[i].z += e * vv.z;
            nv[i].w += e * vv.w;
        }
    }

    // tree-reduce waves {2,3} -> {0,1}, then 1 -> 0
    if (w >= 2) {
#pragma unroll
        for (int i = 0; i < 16; ++i) {
            shn[w - 2][lane][4 * i + 0] = nv[i].x;
            shn[w - 2][lane][4 * i + 1] = nv[i].y;
            shn[w - 2][lane][4 * i + 2] = nv[i].z;
            shn[w - 2][lane][4 * i + 3] = nv[i].w;
        }
        shd[w - 2][lane] = den;
    }
    __syncthreads();
    if (w < 2) {
#pragma unroll
        for (int i = 0; i < 16; ++i) {
            nv[i].x += shn[w][lane][4 * i + 0];
            nv[i].y += shn[w][lane][4 * i + 1];
            nv[i].z += shn[w][lane][4 * i + 2];
            nv[i].w += shn[w][lane][4 * i + 3];
        }
        den += shd[w][lane];
    }
    __syncthreads();
    if (w == 1) {
#pragma unroll
        for (int i = 0; i < 16; ++i) {
            shn[0][lane][4 * i + 0] = nv[i].x;
            shn[0][lane][4 * i + 1] = nv[i].y;
            shn[0][lane][4 * i + 2] = nv[i].z;
            shn[0][lane][4 * i + 3] = nv[i].w;
        }
        shd[0][lane] = den;
    }
    __syncthreads();
    if (w == 0) {
#pragma unroll
        for (int i = 0; i < 16; ++i) {
            nv[i].x += shn[0][lane][4 * i + 0];
            nv[i].y += shn[0][lane][4 * i + 1];
            nv[i].z += shn[0][lane][4 * i + 2];
            nv[i].w += shn[0][lane][4 * i + 3];
        }
        den += shd[0][lane];
        float4* np_ = (float4*)(num_part + ((size_t)blockIdx.y * NROWS + grow) * DK);
#pragma unroll
        for (int i = 0; i < 16; ++i) np_[i] = nv[i];
        den_part[blockIdx.y * NROWS + grow] = den;
    }
}

// ---------------------------------------------------------------------------
// Kernel 3: finalize  out[row][d] = sum_p num_part[p][row][d] / sum_p den_part[p][row]
// ---------------------------------------------------------------------------
__global__ __launch_bounds__(256) void finalize_kernel(
    const float* __restrict__ num_part, const float* __restrict__ den_part,
    float* __restrict__ out)
{
    const int idx = blockIdx.x * 256 + threadIdx.x;   // < NROWS*DK
    const int row = idx >> 6;
    float n = 0.f, d = 0.f;
#pragma unroll
    for (int p = 0; p < JS_OUT; ++p) {
        n += num_part[(size_t)p * NROWS * DK + idx];
        d += den_part[p * NROWS + row];
    }
    out[idx] = n / d;
}

// ---------------------------------------------------------------------------
extern "C" void kernel_launch(void* const* d_in, const int* in_sizes, int n_in,
                              void* d_out, int out_size, void* d_ws, size_t ws_size,
                              hipStream_t stream)
{
    const float* q  = (const float*)d_in[0];   // [4,4096,256]
    const float* k  = (const float*)d_in[1];   // [4,4096,256]
    const float* v  = (const float*)d_in[2];   // [4,4096,64]
    const float* wq = (const float*)d_in[3];   // [64,256]
    const float* wk = (const float*)d_in[4];   // [64,256]
    float* out = (float*)d_out;                // [4,4096,64]

    // workspace layout (fp32): qp | kp | num_part[4] | den_part[4]  = ~25.4 MB
    float* qp       = (float*)d_ws;
    float* kp       = qp + (size_t)NROWS * DK;
    float* num_part = kp + (size_t)NROWS * DK;
    float* den_part = num_part + (size_t)JS_OUT * NROWS * DK;

    proj_kernel<<<dim3(NROWS / 16, 2), 256, 0, stream>>>(q, k, wq, wk, qp, kp);
    attn_partial<<<dim3(NROWS / 64, JS_OUT), 256, 0, stream>>>(qp, kp, v, num_part, den_part);
    finalize_kernel<<<dim3(NROWS * DK / 256), 256, 0, stream>>>(num_part, den_part, out);
}

// Round 2
// 166.838 us; speedup vs baseline: 8.0275x; 8.0275x over previous
//
#include <hip/hip_runtime.h>
#include <math.h>

// B=4, S=4096, d_model=256, d_k=d_v=64
#define B_    4
#define S_    4096
#define DM    256
#define DK    64
#define NROWS (B_ * S_)        // 16384

typedef __attribute__((ext_vector_type(8))) short bfrag;   // 8 bf16 (4 VGPRs)
typedef __attribute__((ext_vector_type(4))) float ffrag;   // 4 f32 acc

// f32 -> bf16 round-to-nearest-even (inputs finite)
__device__ __forceinline__ unsigned bf16_rne_hi(float x) {
    unsigned u = __float_as_uint(x);
    return u + 0x7fffu + ((u >> 16) & 1u);   // bf16 in high 16 bits
}
__device__ __forceinline__ unsigned short f2bf(float x) {
    return (unsigned short)(bf16_rne_hi(x) >> 16);
}
__device__ __forceinline__ unsigned pack_bf16x2(float lo, float hi) {
    return (bf16_rne_hi(hi) & 0xffff0000u) | (bf16_rne_hi(lo) >> 16);
}

// ---------------------------------------------------------------------------
// Prep: vT_perm[b][d][pos] = bf16(v[b][key][d]) with per-32-tile permutation
// pos=2c -> key c, pos=2c+1 -> key c+16  (matches P pair-packing in attn).
// Blocks 256..257 convert w_q / w_k to bf16.
// ---------------------------------------------------------------------------
__global__ __launch_bounds__(256) void prep_kernel(
    const float* __restrict__ v, const float* __restrict__ wq,
    const float* __restrict__ wk, unsigned short* __restrict__ vT,
    unsigned short* __restrict__ wqb, unsigned short* __restrict__ wkb)
{
    const int blk = blockIdx.x;
    if (blk < 256) {
        __shared__ float tile[64][65];
        const int b = blk >> 6, s0 = (blk & 63) * 64;
        const int lane = threadIdx.x & 63, w = threadIdx.x >> 6;
#pragma unroll
        for (int i = 0; i < 16; ++i) {
            const int sl = i * 4 + w;
            tile[sl][lane] = v[(b * S_ + s0 + sl) * DK + lane];
        }
        __syncthreads();
#pragma unroll
        for (int i = 0; i < 16; ++i) {
            const int d = i * 4 + w;
            const int t32 = lane >> 5, pos = lane & 31;
            const int keyl = t32 * 32 + ((pos & 1) ? (pos >> 1) + 16 : (pos >> 1));
            vT[(b * DK + d) * S_ + s0 + lane] = f2bf(tile[keyl][d]);
        }
    } else {
        const float* src = (blk == 256) ? wq : wk;
        unsigned short* dst = (blk == 256) ? wqb : wkb;
        for (int i = threadIdx.x; i < DK * DM; i += 256) dst[i] = f2bf(src[i]);
    }
}

// ---------------------------------------------------------------------------
// Projection via MFMA: o = bf16( relu( x . w^T ) * scale ), x f32->bf16 inline.
// Wave = 32 rows; block = 4 waves = 128 rows. blockIdx.y: 0 -> q (scale 1/8),
// 1 -> k (scale 1).
// ---------------------------------------------------------------------------
__global__ __launch_bounds__(256) void proj_mfma(
    const float* __restrict__ q, const float* __restrict__ k,
    const unsigned short* __restrict__ wqb, const unsigned short* __restrict__ wkb,
    unsigned short* __restrict__ qpb, unsigned short* __restrict__ kpb)
{
    const float* x;
    const unsigned short* wb;
    unsigned short* o;
    float scale;
    if (blockIdx.y == 0) { x = q; wb = wqb; o = qpb; scale = 0.125f; }
    else                 { x = k; wb = wkb; o = kpb; scale = 1.0f;   }

    const int lane = threadIdx.x & 63, w = threadIdx.x >> 6;
    const int m = lane & 15, quad = lane >> 4;
    const int rows0 = blockIdx.x * 128 + w * 32;

    ffrag acc[2][4];
#pragma unroll
    for (int mt = 0; mt < 2; ++mt)
#pragma unroll
        for (int dt = 0; dt < 4; ++dt) acc[mt][dt] = (ffrag)(0.0f);

#pragma unroll 2
    for (int kf = 0; kf < 8; ++kf) {
        bfrag A[2];
#pragma unroll
        for (int mt = 0; mt < 2; ++mt) {
            const float4* xr = (const float4*)&x[(rows0 + mt * 16 + m) * DM + kf * 32 + quad * 8];
            const float4 a0 = xr[0], a1 = xr[1];
            union { bfrag v; unsigned u[4]; } pk;
            pk.u[0] = pack_bf16x2(a0.x, a0.y);
            pk.u[1] = pack_bf16x2(a0.z, a0.w);
            pk.u[2] = pack_bf16x2(a1.x, a1.y);
            pk.u[3] = pack_bf16x2(a1.z, a1.w);
            A[mt] = pk.v;
        }
#pragma unroll
        for (int dt = 0; dt < 4; ++dt) {
            const bfrag Bf = *(const bfrag*)&wb[(dt * 16 + m) * DM + kf * 32 + quad * 8];
            acc[0][dt] = __builtin_amdgcn_mfma_f32_16x16x32_bf16(A[0], Bf, acc[0][dt], 0, 0, 0);
            acc[1][dt] = __builtin_amdgcn_mfma_f32_16x16x32_bf16(A[1], Bf, acc[1][dt], 0, 0, 0);
        }
    }
#pragma unroll
    for (int mt = 0; mt < 2; ++mt)
#pragma unroll
        for (int dt = 0; dt < 4; ++dt)
#pragma unroll
            for (int r = 0; r < 4; ++r)
                o[(rows0 + mt * 16 + quad * 4 + r) * DK + dt * 16 + m] =
                    f2bf(fmaxf(acc[mt][dt][r], 0.0f) * scale);
}

// ---------------------------------------------------------------------------
// Attention: block = 4 waves, all on the same 32 q-rows; wave w covers keys
// [(gy*4+w)*512, +512) in KT=32 tiles. One-pass num/den (no max-rescale:
// scores bounded). P transform C->A layout via wave-local LDS (no barriers
// in main loop). Epilogue: LDS tree-reduce 4 waves -> global partial (gy).
// ---------------------------------------------------------------------------
__global__ __launch_bounds__(256) void attn_mfma(
    const unsigned short* __restrict__ qp, const unsigned short* __restrict__ kp,
    const unsigned short* __restrict__ vT, float* __restrict__ num_part,
    float* __restrict__ den_part)
{
    __shared__ __align__(16) unsigned short Plds[4][32 * 40]; // stride 40 ush = 20 words
    __shared__ float red[2][2560];                            // 2048 num + 512 den

    const int lane = threadIdx.x & 63, w = threadIdx.x >> 6;
    const int m = lane & 15, quad = lane >> 4;
    const int qg = blockIdx.x;            // 0..511
    const int qbase = qg * 32;
    const int b = qg >> 7;                // 128 q-groups per batch
    const int kstart = (blockIdx.y * 4 + w) * 512;

    // resident qp A-frags (bf16, 1/8 pre-folded)
    bfrag qa[2][2];
#pragma unroll
    for (int mt = 0; mt < 2; ++mt)
#pragma unroll
        for (int kf = 0; kf < 2; ++kf)
            qa[mt][kf] = *(const bfrag*)&qp[(qbase + mt * 16 + m) * DK + kf * 32 + quad * 8];

    ffrag oacc[2][4];
    float dacc[2][4];
#pragma unroll
    for (int mt = 0; mt < 2; ++mt) {
#pragma unroll
        for (int dt = 0; dt < 4; ++dt) oacc[mt][dt] = (ffrag)(0.0f);
#pragma unroll
        for (int r = 0; r < 4; ++r) dacc[mt][r] = 0.0f;
    }

    const unsigned short* kpb = kp + b * S_ * DK;
    const unsigned short* vtb = vT + b * DK * S_;
    unsigned short* Pw = Plds[w];

#pragma unroll 1
    for (int jj = 0; jj < 16; ++jj) {
        const int kb = kstart + jj * 32;
        // issue all 8 global frag loads up front
        bfrag kbf[2][2], vbf[4];
#pragma unroll
        for (int kt = 0; kt < 2; ++kt)
#pragma unroll
            for (int kf = 0; kf < 2; ++kf)
                kbf[kt][kf] = *(const bfrag*)&kpb[(kb + kt * 16 + m) * DK + kf * 32 + quad * 8];
#pragma unroll
        for (int dt = 0; dt < 4; ++dt)
            vbf[dt] = *(const bfrag*)&vtb[(dt * 16 + m) * S_ + kb + quad * 8];

        // scores S[q = mt*16+quad*4+r][key = kb + kt*16 + m]
        ffrag s[2][2];
#pragma unroll
        for (int mt = 0; mt < 2; ++mt)
#pragma unroll
            for (int kt = 0; kt < 2; ++kt) {
                ffrag t = __builtin_amdgcn_mfma_f32_16x16x32_bf16(qa[mt][0], kbf[kt][0], (ffrag)(0.0f), 0, 0, 0);
                s[mt][kt] = __builtin_amdgcn_mfma_f32_16x16x32_bf16(qa[mt][1], kbf[kt][1], t, 0, 0, 0);
            }

        // exp, mask col 0, den, pack pairs (key c, key c+16) -> LDS
        const bool mask0 = (kb == 0) && (m == 0);
#pragma unroll
        for (int mt = 0; mt < 2; ++mt)
#pragma unroll
            for (int r = 0; r < 4; ++r) {
                float e0 = __expf(s[mt][0][r]);
                float e1 = __expf(s[mt][1][r]);
                if (mask0) e0 = 0.0f;
                dacc[mt][r] += e0 + e1;
                *(unsigned*)&Pw[(mt * 16 + quad * 4 + r) * 40 + m * 2] = pack_bf16x2(e0, e1);
            }

        // P A-frags from LDS (wave-local; HW orders DS ops per wave)
        bfrag pa[2];
#pragma unroll
        for (int mt = 0; mt < 2; ++mt)
            pa[mt] = *(const bfrag*)&Pw[(mt * 16 + m) * 40 + quad * 8];

#pragma unroll
        for (int dt = 0; dt < 4; ++dt) {
            oacc[0][dt] = __builtin_amdgcn_mfma_f32_16x16x32_bf16(pa[0], vbf[dt], oacc[0][dt], 0, 0, 0);
            oacc[1][dt] = __builtin_amdgcn_mfma_f32_16x16x32_bf16(pa[1], vbf[dt], oacc[1][dt], 0, 0, 0);
        }
    }

    // reduce den over the 16 col-lanes (keys) within each quad group
#pragma unroll
    for (int mt = 0; mt < 2; ++mt)
#pragma unroll
        for (int r = 0; r < 4; ++r) {
            float d = dacc[mt][r];
            d += __shfl_xor(d, 1, 64);
            d += __shfl_xor(d, 2, 64);
            d += __shfl_xor(d, 4, 64);
            d += __shfl_xor(d, 8, 64);
            dacc[mt][r] = d;
        }

    // cross-wave tree reduce: {2,3} -> {0,1}, then 1 -> 0
    __syncthreads();
    if (w >= 2) {
#pragma unroll
        for (int mt = 0; mt < 2; ++mt) {
#pragma unroll
            for (int dt = 0; dt < 4; ++dt)
#pragma unroll
                for (int r = 0; r < 4; ++r)
                    red[w - 2][((mt * 4 + dt) * 4 + r) * 64 + lane] = oacc[mt][dt][r];
#pragma unroll
            for (int r = 0; r < 4; ++r)
                red[w - 2][2048 + (mt * 4 + r) * 64 + lane] = dacc[mt][r];
        }
    }
    __syncthreads();
    if (w < 2) {
#pragma unroll
        for (int mt = 0; mt < 2; ++mt) {
#pragma unroll
            for (int dt = 0; dt < 4; ++dt)
#pragma unroll
                for (int r = 0; r < 4; ++r)
                    oacc[mt][dt][r] += red[w][((mt * 4 + dt) * 4 + r) * 64 + lane];
#pragma unroll
            for (int r = 0; r < 4; ++r)
                dacc[mt][r] += red[w][2048 + (mt * 4 + r) * 64 + lane];
        }
    }
    __syncthreads();
    if (w == 1) {
#pragma unroll
        for (int mt = 0; mt < 2; ++mt) {
#pragma unroll
            for (int dt = 0; dt < 4; ++dt)
#pragma unroll
                for (int r = 0; r < 4; ++r)
                    red[0][((mt * 4 + dt) * 4 + r) * 64 + lane] = oacc[mt][dt][r];
#pragma unroll
            for (int r = 0; r < 4; ++r)
                red[0][2048 + (mt * 4 + r) * 64 + lane] = dacc[mt][r];
        }
    }
    __syncthreads();
    if (w == 0) {
        const int gy = blockIdx.y;
#pragma unroll
        for (int mt = 0; mt < 2; ++mt) {
#pragma unroll
            for (int dt = 0; dt < 4; ++dt)
#pragma unroll
                for (int r = 0; r < 4; ++r) {
                    const float nv = oacc[mt][dt][r] + red[0][((mt * 4 + dt) * 4 + r) * 64 + lane];
                    num_part[(size_t)gy * NROWS * DK +
                             (qbase + mt * 16 + quad * 4 + r) * DK + dt * 16 + m] = nv;
                }
#pragma unroll
            for (int r = 0; r < 4; ++r) {
                const float dv = dacc[mt][r] + red[0][2048 + (mt * 4 + r) * 64 + lane];
                if (m == 0)
                    den_part[gy * NROWS + qbase + mt * 16 + quad * 4 + r] = dv;
            }
        }
    }
}

// ---------------------------------------------------------------------------
__global__ __launch_bounds__(256) void finalize_kernel(
    const float* __restrict__ num_part, const float* __restrict__ den_part,
    float* __restrict__ out)
{
    const int idx = blockIdx.x * 256 + threadIdx.x;
    const int row = idx >> 6;
    const float n = num_part[idx] + num_part[(size_t)NROWS * DK + idx];
    const float d = den_part[row] + den_part[NROWS + row];
    out[idx] = n / d;
}

// ---------------------------------------------------------------------------
extern "C" void kernel_launch(void* const* d_in, const int* in_sizes, int n_in,
                              void* d_out, int out_size, void* d_ws, size_t ws_size,
                              hipStream_t stream)
{
    const float* q  = (const float*)d_in[0];
    const float* k  = (const float*)d_in[1];
    const float* v  = (const float*)d_in[2];
    const float* wq = (const float*)d_in[3];
    const float* wk = (const float*)d_in[4];
    float* out = (float*)d_out;

    // ws layout (bytes): qpb 2M | kpb 2M | wqb 32K | wkb 32K | vT 2M |
    //                    num_part 8M | den_part 128K   (~14.9 MB total)
    char* p = (char*)d_ws;
    unsigned short* qpb = (unsigned short*)p;               p += (size_t)NROWS * DK * 2;
    unsigned short* kpb = (unsigned short*)p;               p += (size_t)NROWS * DK * 2;
    unsigned short* wqb = (unsigned short*)p;               p += DK * DM * 2;
    unsigned short* wkb = (unsigned short*)p;               p += DK * DM * 2;
    unsigned short* vT  = (unsigned short*)p;               p += (size_t)B_ * DK * S_ * 2;
    float* num_part     = (float*)p;                        p += (size_t)2 * NROWS * DK * 4;
    float* den_part     = (float*)p;

    prep_kernel<<<258, 256, 0, stream>>>(v, wq, wk, vT, wqb, wkb);
    proj_mfma<<<dim3(128, 2), 256, 0, stream>>>(q, k, wqb, wkb, qpb, kpb);
    attn_mfma<<<dim3(512, 2), 256, 0, stream>>>(qpb, kpb, vT, num_part, den_part);
    finalize_kernel<<<NROWS * DK / 256, 256, 0, stream>>>(num_part, den_part, out);
}